// Round 4
// baseline (569.352 us; speedup 1.0000x reference)
//
#include <hip/hip_runtime.h>

#define RDIM 1152
#define CIN  8
#define COUT 16
#define CDIM 10
#define BDIM 256
#define BLOCK 384
#define UNITS 12                 // (1152 rows * 4 o-quarters) / 384 threads
#define NWAVES (BLOCK / 64)
#define NWG (CDIM * BDIM)        // 2560, divisible by 8
#define EPS 1e-7f

__global__ __launch_bounds__(BLOCK, 3) void caps_route(
    const float* __restrict__ x, const float* __restrict__ W,
    float* __restrict__ out)
{
    // XCD-aware bijective swizzle (2560 = 8 * 320): W[c] stays L2-resident per XCD
    const int orig = blockIdx.x;
    const int wg   = (orig & 7) * (NWG / 8) + (orig >> 3);
    const int c    = wg / BDIM;
    const int b    = wg % BDIM;

    const int tid  = threadIdx.x;
    const int lane = tid & 63;
    const int wave = tid >> 6;
    const int oq   = tid & 3;     // owned o-quarter (o = oq*4 .. oq*4+3)
    const int rsub = tid >> 2;    // 0..95 row-within-group

    __shared__ float red[NWAVES][COUT];
    __shared__ float scalm[NWAVES];
    __shared__ float scalz[NWAVES];
    __shared__ float vout[COUT];

    const float* __restrict__ Wc = W + (size_t)c * RDIM * CIN * COUT;
    const float* __restrict__ xb = x + (size_t)b * RDIM * CIN;

    float uh[UNITS][4];   // u_hat[r_k][oq*4 .. +3] — register resident
    float bb[UNITS];      // routing logits (duplicated x4 across oq lanes)

    // ---- Phase A: u_hat (coalesced W: 4 lanes cover 64B, groups stride 512B) ----
    #pragma unroll
    for (int k = 0; k < UNITS; ++k) {
        const int r = k * 96 + rsub;
        const float4* xp = (const float4*)(xb + (size_t)r * CIN);
        float4 x0 = xp[0], x1 = xp[1];
        float xr[CIN] = {x0.x, x0.y, x0.z, x0.w, x1.x, x1.y, x1.z, x1.w};

        const float* wrow = Wc + (size_t)r * (CIN * COUT) + oq * 4;
        float a0 = 0.f, a1 = 0.f, a2 = 0.f, a3 = 0.f;
        #pragma unroll
        for (int i = 0; i < CIN; ++i) {
            float4 w = *(const float4*)(wrow + i * COUT);
            a0 = fmaf(xr[i], w.x, a0);
            a1 = fmaf(xr[i], w.y, a1);
            a2 = fmaf(xr[i], w.z, a2);
            a3 = fmaf(xr[i], w.w, a3);
        }
        uh[k][0] = a0; uh[k][1] = a1; uh[k][2] = a2; uh[k][3] = a3;
        bb[k] = 0.0f;
    }

    // ---- Phase B: 3 routing iterations, all state in registers ----
    #pragma unroll
    for (int it = 0; it < 3; ++it) {
        // 1) softmax max over R
        float m = bb[0];
        #pragma unroll
        for (int k = 1; k < UNITS; ++k) m = fmaxf(m, bb[k]);
        #pragma unroll
        for (int off = 32; off >= 1; off >>= 1) m = fmaxf(m, __shfl_xor(m, off));
        if (lane == 0) scalm[wave] = m;
        __syncthreads();
        m = scalm[0];
        #pragma unroll
        for (int w2 = 1; w2 < NWAVES; ++w2) m = fmaxf(m, scalm[w2]);

        // 2) e = exp(b-m) (transient); partial Z and weighted o-slice sums
        float Zp = 0.f, sp0 = 0.f, sp1 = 0.f, sp2 = 0.f, sp3 = 0.f;
        #pragma unroll
        for (int k = 0; k < UNITS; ++k) {
            float e = expf(bb[k] - m);
            Zp += e;
            sp0 = fmaf(e, uh[k][0], sp0);
            sp1 = fmaf(e, uh[k][1], sp1);
            sp2 = fmaf(e, uh[k][2], sp2);
            sp3 = fmaf(e, uh[k][3], sp3);
        }
        // butterfly over same-oq lanes (xor 4..32 keeps lane%4 invariant);
        // each same-oq set covers 192 distinct rows exactly once
        #pragma unroll
        for (int off = 32; off >= 4; off >>= 1) {
            Zp  += __shfl_xor(Zp, off);
            sp0 += __shfl_xor(sp0, off);
            sp1 += __shfl_xor(sp1, off);
            sp2 += __shfl_xor(sp2, off);
            sp3 += __shfl_xor(sp3, off);
        }
        if (lane < 4) {   // lane == oq; slice o = lane*4..+3
            red[wave][lane * 4 + 0] = sp0;
            red[wave][lane * 4 + 1] = sp1;
            red[wave][lane * 4 + 2] = sp2;
            red[wave][lane * 4 + 3] = sp3;
            if (lane == 0) scalz[wave] = Zp;
        }
        __syncthreads();

        // 3) wave 0, 16 lanes finalize: s -> squash -> vout (one pass)
        if (wave == 0 && lane < COUT) {
            float Z = 0.f;
            #pragma unroll
            for (int w2 = 0; w2 < NWAVES; ++w2) Z += scalz[w2];
            float s = 0.f;
            #pragma unroll
            for (int w2 = 0; w2 < NWAVES; ++w2) s += red[w2][lane];
            s /= Z;
            float sn = s * s;
            #pragma unroll
            for (int off = 1; off < 16; off <<= 1) sn += __shfl_xor(sn, off);
            const float scale = (sn / (1.0f + sn)) / sqrtf(sn + EPS);
            vout[lane] = s * scale;
        }
        __syncthreads();

        // broadcast read of this thread's o-quarter of v
        const float4 vv = *(const float4*)&vout[oq * 4];

        // 4) agreement update: bb[k] += u_r . v (completed across 4 oq lanes)
        if (it < 2) {
            #pragma unroll
            for (int k = 0; k < UNITS; ++k) {
                float a = uh[k][0] * vv.x;
                a = fmaf(uh[k][1], vv.y, a);
                a = fmaf(uh[k][2], vv.z, a);
                a = fmaf(uh[k][3], vv.w, a);
                a += __shfl_xor(a, 1);
                a += __shfl_xor(a, 2);
                bb[k] += a;
            }
            __syncthreads();  // protect red/scalm/scalz before next iter writes
        }
    }

    // ---- write output [C,B,1,1,O]: 4 threads x float4 (vout still valid) ----
    if (tid < 4) {
        float* op = out + ((size_t)c * BDIM + b) * COUT + tid * 4;
        *(float4*)op = *(const float4*)&vout[tid * 4];
    }
}

extern "C" void kernel_launch(void* const* d_in, const int* in_sizes, int n_in,
                              void* d_out, int out_size, void* d_ws, size_t ws_size,
                              hipStream_t stream) {
    const float* x = (const float*)d_in[0];   // [256,1152,8]
    const float* W = (const float*)d_in[1];   // [10,1152,8,16]
    float* out = (float*)d_out;               // [10,256,1,1,16]

    dim3 grid(NWG);
    dim3 block(BLOCK);
    caps_route<<<grid, block, 0, stream>>>(x, W, out);
}

// Round 5
// 97.961 us; speedup vs baseline: 5.8120x; 5.8120x over previous
//
#include <hip/hip_runtime.h>
#include <hip/hip_fp16.h>

#define RDIM 1152
#define CIN  8
#define COUT 16
#define CDIM 10
#define BDIM 256
#define NB   2                    // batches per block
#define BLOCK 384
#define UNITS 12                  // rows per (oq,rsub) thread: 1152/96
#define NWAVES (BLOCK / 64)
#define NPAIR (BDIM / NB)         // 128
#define NWG (CDIM * NPAIR)        // 1280 = 8*160
#define PLANE 1156                // 1152 + 4 pad (shifts plane base by 8 banks)
#define EPS 1e-7f

__global__ __launch_bounds__(BLOCK) void caps_route(
    const float* __restrict__ x, const float* __restrict__ W,
    float* __restrict__ out)
{
    // XCD-aware bijective swizzle (1280 = 8*160): blocks on one XCD share c
    const int orig = blockIdx.x;
    const int wg   = (orig & 7) * (NWG / 8) + (orig >> 3);
    const int c    = wg / NPAIR;
    const int bp   = wg % NPAIR;
    const int b0   = bp * NB;

    const int tid  = threadIdx.x;
    const int lane = tid & 63;
    const int wave = tid >> 6;
    const int oq   = tid & 3;     // owned o-quarter
    const int rsub = tid >> 2;    // 0..95

    // u_hat, fp16, transposed into o-quad planes: uhT[nb][oq][r] = 4 halves
    __shared__ uint2 uhT[NB][4][PLANE];               // 73,984 B
    __shared__ float red[NB][NWAVES][COUT];
    __shared__ float scalm[NB][NWAVES];
    __shared__ float scalz[NB][NWAVES];
    __shared__ __align__(16) float vout[NB][COUT];

    const float* __restrict__ Wc  = W + (size_t)c * RDIM * CIN * COUT;
    const float* __restrict__ xb0 = x + (size_t)b0 * RDIM * CIN;
    const float* __restrict__ xb1 = xb0 + RDIM * CIN;

    // ---------- Phase A: u_hat -> LDS fp16 (W row read once, used for 2 b's) ----------
    #pragma unroll
    for (int k = 0; k < UNITS; ++k) {
        const int r = k * 96 + rsub;
        const float4* xp0 = (const float4*)(xb0 + (size_t)r * CIN);
        const float4* xp1 = (const float4*)(xb1 + (size_t)r * CIN);
        float4 p00 = xp0[0], p01 = xp0[1];
        float4 p10 = xp1[0], p11 = xp1[1];
        float xr0[CIN] = {p00.x, p00.y, p00.z, p00.w, p01.x, p01.y, p01.z, p01.w};
        float xr1[CIN] = {p10.x, p10.y, p10.z, p10.w, p11.x, p11.y, p11.z, p11.w};

        const float* wrow = Wc + (size_t)r * (CIN * COUT) + oq * 4;
        float a00 = 0.f, a01 = 0.f, a02 = 0.f, a03 = 0.f;
        float a10 = 0.f, a11 = 0.f, a12 = 0.f, a13 = 0.f;
        #pragma unroll
        for (int i = 0; i < CIN; ++i) {
            float4 w = *(const float4*)(wrow + i * COUT);
            a00 = fmaf(xr0[i], w.x, a00); a01 = fmaf(xr0[i], w.y, a01);
            a02 = fmaf(xr0[i], w.z, a02); a03 = fmaf(xr0[i], w.w, a03);
            a10 = fmaf(xr1[i], w.x, a10); a11 = fmaf(xr1[i], w.y, a11);
            a12 = fmaf(xr1[i], w.z, a12); a13 = fmaf(xr1[i], w.w, a13);
        }
        __half2 hA0 = __floats2half2_rn(a00, a01), hB0 = __floats2half2_rn(a02, a03);
        __half2 hA1 = __floats2half2_rn(a10, a11), hB1 = __floats2half2_rn(a12, a13);
        uhT[0][oq][r] = make_uint2(*(const unsigned*)&hA0, *(const unsigned*)&hB0);
        uhT[1][oq][r] = make_uint2(*(const unsigned*)&hA1, *(const unsigned*)&hB1);
    }
    __syncthreads();

    // ---------- Phase B: 2 concurrent routings ----------
    float bb[NB][UNITS];
    #pragma unroll
    for (int nb = 0; nb < NB; ++nb)
        #pragma unroll
        for (int k = 0; k < UNITS; ++k) bb[nb][k] = 0.0f;

    #pragma unroll
    for (int it = 0; it < 3; ++it) {
        // 1) softmax max over R (duplicates across oq lanes are identical)
        #pragma unroll
        for (int nb = 0; nb < NB; ++nb) {
            float m = bb[nb][0];
            #pragma unroll
            for (int k = 1; k < UNITS; ++k) m = fmaxf(m, bb[nb][k]);
            #pragma unroll
            for (int off = 32; off >= 1; off >>= 1) m = fmaxf(m, __shfl_xor(m, off));
            if (lane == 0) scalm[nb][wave] = m;
        }
        __syncthreads();
        float mm[NB];
        #pragma unroll
        for (int nb = 0; nb < NB; ++nb) {
            float m = scalm[nb][0];
            #pragma unroll
            for (int w2 = 1; w2 < NWAVES; ++w2) m = fmaxf(m, scalm[nb][w2]);
            mm[nb] = m;
        }

        // 2) e = exp(b-m); partial Z and weighted o-slice sums from LDS u_hat
        #pragma unroll
        for (int nb = 0; nb < NB; ++nb) {
            float Zp = 0.f, s0 = 0.f, s1 = 0.f, s2 = 0.f, s3 = 0.f;
            #pragma unroll
            for (int k = 0; k < UNITS; ++k) {
                const int r = k * 96 + rsub;
                uint2 raw = uhT[nb][oq][r];
                float2 fA = __half22float2(*(const __half2*)&raw.x);
                float2 fB = __half22float2(*(const __half2*)&raw.y);
                float e = expf(bb[nb][k] - mm[nb]);
                Zp += e;
                s0 = fmaf(e, fA.x, s0); s1 = fmaf(e, fA.y, s1);
                s2 = fmaf(e, fB.x, s2); s3 = fmaf(e, fB.y, s3);
            }
            // butterfly over same-oq lanes: each row counted exactly once
            #pragma unroll
            for (int off = 32; off >= 4; off >>= 1) {
                Zp += __shfl_xor(Zp, off);
                s0 += __shfl_xor(s0, off);
                s1 += __shfl_xor(s1, off);
                s2 += __shfl_xor(s2, off);
                s3 += __shfl_xor(s3, off);
            }
            if (lane < 4) {   // lane == oq here
                red[nb][wave][lane * 4 + 0] = s0;
                red[nb][wave][lane * 4 + 1] = s1;
                red[nb][wave][lane * 4 + 2] = s2;
                red[nb][wave][lane * 4 + 3] = s3;
                if (lane == 0) scalz[nb][wave] = Zp;
            }
        }
        __syncthreads();

        // 3) finalize + squash: wave 0, lanes 0-15 -> batch 0, lanes 32-47 -> batch 1
        if (wave == 0 && (lane & 31) < COUT) {
            const int nb = lane >> 5;
            const int o  = lane & 31;
            float Z = 0.f;
            #pragma unroll
            for (int w2 = 0; w2 < NWAVES; ++w2) Z += scalz[nb][w2];
            float s = 0.f;
            #pragma unroll
            for (int w2 = 0; w2 < NWAVES; ++w2) s += red[nb][w2][o];
            s /= Z;
            float sn = s * s;
            #pragma unroll
            for (int off = 1; off < 16; off <<= 1) sn += __shfl_xor(sn, off);
            const float scale = (sn / (1.0f + sn)) / sqrtf(sn + EPS);
            vout[nb][o] = s * scale;
        }
        __syncthreads();

        // 4) agreement update: bb += u_r . v (completed across the 4 oq lanes)
        if (it < 2) {
            #pragma unroll
            for (int nb = 0; nb < NB; ++nb) {
                const float4 vv = *(const float4*)&vout[nb][oq * 4];
                #pragma unroll
                for (int k = 0; k < UNITS; ++k) {
                    const int r = k * 96 + rsub;
                    uint2 raw = uhT[nb][oq][r];
                    float2 fA = __half22float2(*(const __half2*)&raw.x);
                    float2 fB = __half22float2(*(const __half2*)&raw.y);
                    float a = fA.x * vv.x;
                    a = fmaf(fA.y, vv.y, a);
                    a = fmaf(fB.x, vv.z, a);
                    a = fmaf(fB.y, vv.w, a);
                    a += __shfl_xor(a, 1);
                    a += __shfl_xor(a, 2);
                    bb[nb][k] += a;
                }
            }
        }
        // no extra barrier needed: next iter's scalm/red writes are separated
        // from this iter's readers by sync points 1 and 2 of the next iteration
    }

    // ---------- write output [C,B,1,1,O]: 8 threads x float4 ----------
    if (tid < 8) {
        const int nb = tid >> 2, q = tid & 3;
        float* op = out + ((size_t)c * BDIM + b0 + nb) * COUT + q * 4;
        *(float4*)op = *(const float4*)&vout[nb][q * 4];
    }
}

extern "C" void kernel_launch(void* const* d_in, const int* in_sizes, int n_in,
                              void* d_out, int out_size, void* d_ws, size_t ws_size,
                              hipStream_t stream) {
    const float* x = (const float*)d_in[0];   // [256,1152,8]
    const float* W = (const float*)d_in[1];   // [10,1152,8,16]
    float* out = (float*)d_out;               // [10,256,1,1,16]

    dim3 grid(NWG);
    dim3 block(BLOCK);
    caps_route<<<grid, block, 0, stream>>>(x, W, out);
}